// Round 1
// baseline (1740.881 us; speedup 1.0000x reference)
//
#include <hip/hip_runtime.h>
#include <hip/hip_bf16.h>

// CWRRTCell fp32 baseline.
// Pipeline:
//  1. ln_kernel<ADD=1>  : x_in = x+delta (stored), y = LN1(x_in)
//  2. memupd_kernel     : updated_mem = [mem[:,1:,:], x_in]  -> d_out
//  3. gemm QSCALE       : q = (y@wq + bq)/8                 [B,512]x[512,512]
//  4. gemm NONE (WT)    : qk[b,h,e] = sum_d q[b,h,d]*wk[e,h,d]   per-head
//  5. attn_kernel       : s = mem_upd . qk  (bk term is constant over m ->
//                         softmax-invariant, dropped), softmax,
//                         ctx[b,h,e] = sum_m attn*mem_upd   (in-place over qk)
//  6. gemm BIAS         : o[b,h,d] = sum_e ctx*wv + bv          per-head
//  7. gemm RES          : x_mid = o@wo + bo + x_in
//  8. ln_kernel<ADD=0>  : y = LN2(x_mid)
//  9. gemm GELU         : hidden = gelu(y@w1 + b1)
// 10. gemm FINAL        : x_out = hidden@w2 + b2 + x_mid -> d_out,
//                         new_ssum = ssum*0.9 + x_out*0.1 -> d_out

namespace {

constexpr int Bn = 8192;
constexpr int E  = 512;
constexpr int H  = 8;
constexpr int D  = 64;
constexpr int M  = 16;
constexpr int F  = 2048;

__device__ __forceinline__ float gelu_f(float x) {
  float x3 = x * x * x;
  float t  = tanhf(0.7978845608028654f * (x + 0.044715f * x3));
  return 0.5f * x * (1.0f + t);
}

// ---------------- LayerNorm (one block per row, 256 thr, float2/thread) ----
template <bool ADD>
__global__ __launch_bounds__(256)
void ln_kernel(const float* __restrict__ a, const float* __restrict__ bIn,
               const float* __restrict__ scale, const float* __restrict__ bias,
               float* __restrict__ xin_out, float* __restrict__ y_out) {
  const int row = blockIdx.x;
  const int t   = threadIdx.x;
  float2 v = ((const float2*)(a + (size_t)row * E))[t];
  if constexpr (ADD) {
    float2 w = ((const float2*)(bIn + (size_t)row * E))[t];
    v.x += w.x; v.y += w.y;
    ((float2*)(xin_out + (size_t)row * E))[t] = v;
  }
  float s = v.x + v.y;
  float q = v.x * v.x + v.y * v.y;
#pragma unroll
  for (int o = 32; o > 0; o >>= 1) {
    s += __shfl_down(s, o);
    q += __shfl_down(q, o);
  }
  __shared__ float red[10];
  const int wave = t >> 6, lane = t & 63;
  if (lane == 0) { red[wave] = s; red[4 + wave] = q; }
  __syncthreads();
  if (t == 0) {
    float ts = red[0] + red[1] + red[2] + red[3];
    float tq = red[4] + red[5] + red[6] + red[7];
    float mu  = ts * (1.0f / E);
    float var = tq * (1.0f / E) - mu * mu;
    red[8] = mu;
    red[9] = rsqrtf(var + 1e-6f);
  }
  __syncthreads();
  const float mu = red[8], rs = red[9];
  float2 sc = ((const float2*)scale)[t];
  float2 bi = ((const float2*)bias)[t];
  float2 y;
  y.x = (v.x - mu) * rs * sc.x + bi.x;
  y.y = (v.y - mu) * rs * sc.y + bi.y;
  ((float2*)(y_out + (size_t)row * E))[t] = y;
}

// ---------------- memory-slot roll: out[b,m,:] = m<15 ? mem[b,m+1,:] : x+delta
__global__ __launch_bounds__(256)
void memupd_kernel(const float4* __restrict__ mem4, const float4* __restrict__ x4,
                   const float4* __restrict__ d4, float4* __restrict__ out4) {
  const size_t total  = (size_t)Bn * M * E / 4;  // 16,777,216 float4
  const size_t stride = (size_t)gridDim.x * blockDim.x;
  for (size_t g = (size_t)blockIdx.x * blockDim.x + threadIdx.x; g < total; g += stride) {
    const int rem = (int)(g & 2047);  // M*E/4 = 2048 per row
    float4 v;
    if (rem < 1920) {                 // m < 15: shift by one slot (+128 f4)
      v = mem4[g + 128];
    } else {                          // m == 15: append x_in
      const size_t b = g >> 11;
      const int    c = rem & 127;
      float4 xv = x4[(b << 7) + c];
      float4 dv = d4[(b << 7) + c];
      v.x = xv.x + dv.x; v.y = xv.y + dv.y; v.z = xv.z + dv.z; v.w = xv.w + dv.w;
    }
    out4[g] = v;
  }
}

// ---------------- attention core (one block per b) -------------------------
__global__ __launch_bounds__(256)
void attn_kernel(const float* __restrict__ umem, float* __restrict__ qkctx) {
  __shared__ float memL[M * E];   // 32 KB
  __shared__ float qkL[H * E];    // 16 KB
  __shared__ float sL[H * M];
  __shared__ float attnL[H * M];
  const int b = blockIdx.x, t = threadIdx.x;

  const float4* um4 = (const float4*)(umem + (size_t)b * (M * E));
#pragma unroll
  for (int i = 0; i < (M * E / 4) / 256; ++i) ((float4*)memL)[t + 256 * i] = um4[t + 256 * i];
  const float4* qk4 = (const float4*)(qkctx + (size_t)b * (H * E));
#pragma unroll
  for (int i = 0; i < (H * E / 4) / 256; ++i) ((float4*)qkL)[t + 256 * i] = qk4[t + 256 * i];
  __syncthreads();

  // scores: 128 (h,m) pairs x 2 e-halves; lane-phased scalar reads (conflict-free)
  {
    const int pair = t >> 1, h = pair >> 4, m = pair & 15, half = t & 1;
    const float* mp = memL + m * E + half * 256;
    const float* qp = qkL + h * E + half * 256;
    float s = 0.f;
    const int ph = t;
    for (int i = 0; i < 256; ++i) {
      const int e = (i + ph) & 255;
      s = fmaf(mp[e], qp[e], s);
    }
    s += __shfl_xor(s, 1);
    if (half == 0) sL[pair] = s;
  }
  __syncthreads();
  if (t < H) {
    float mx = sL[t * 16];
#pragma unroll
    for (int m = 1; m < 16; ++m) mx = fmaxf(mx, sL[t * 16 + m]);
    float ex[16], sum = 0.f;
#pragma unroll
    for (int m = 0; m < 16; ++m) { ex[m] = expf(sL[t * 16 + m] - mx); sum += ex[m]; }
    const float inv = 1.0f / sum;
#pragma unroll
    for (int m = 0; m < 16; ++m) attnL[t * 16 + m] = ex[m] * inv;
  }
  __syncthreads();

  // ctx[h,e] = sum_m attn[h,m] * mem[m,e]  (writes over qk in-place)
  float4* ctx4 = (float4*)(qkctx + (size_t)b * (H * E));
#pragma unroll
  for (int j = 0; j < 4; ++j) {
    const int p4 = t + 256 * j;
    const int h  = p4 >> 7;
    const int e4 = p4 & 127;
    const float* ap = attnL + h * 16;
    float4 c = make_float4(0.f, 0.f, 0.f, 0.f);
#pragma unroll
    for (int m = 0; m < 16; ++m) {
      const float  a  = ap[m];
      const float4 mv = *(const float4*)&memL[m * E + 4 * e4];
      c.x = fmaf(a, mv.x, c.x); c.y = fmaf(a, mv.y, c.y);
      c.z = fmaf(a, mv.z, c.z); c.w = fmaf(a, mv.w, c.w);
    }
    ctx4[p4] = c;
  }
}

// ---------------- generic fp32 GEMM: C = A[BM,K] @ W[K,BN] (+epilogue) ------
enum : int { EPI_NONE = 0, EPI_QSCALE, EPI_BIAS, EPI_RES, EPI_GELU, EPI_FINAL };

template <int TN, int EPI, bool WT>
__global__ __launch_bounds__(256, 2)
void gemm_kernel(const float* __restrict__ A, int lda, int aHead,
                 const float* __restrict__ W, int ldw, int wHead,
                 const float* __restrict__ bias, int bHead,
                 float* __restrict__ C, int ldc, int cHead,
                 int K,
                 const float* __restrict__ res,
                 const float* __restrict__ ssum_in,
                 float* __restrict__ ssum_out) {
  constexpr int BM = 128, BK = 32, BN = 16 * TN;
  __shared__ float As[BK][BM + 4];  // transposed tile As[k][m], +4 pad
  __shared__ float Bs[BK][BN];
  const int t  = threadIdx.x;
  const int tm = t & 15, tn = t >> 4;
  const int m0 = blockIdx.y * BM;
  const int n0 = blockIdx.x * BN;
  const int h  = blockIdx.z;
  A += (size_t)h * aHead;
  W += (size_t)h * wHead;
  C += (size_t)h * cHead;
  const float* bptr = bias + (size_t)h * bHead;

  float acc[8][TN];
#pragma unroll
  for (int i = 0; i < 8; ++i)
#pragma unroll
    for (int j = 0; j < TN; ++j) acc[i][j] = 0.f;

  for (int k0 = 0; k0 < K; k0 += BK) {
    // stage A (transpose to As[k][m]); global-coalesced float4 along k
#pragma unroll
    for (int r = 0; r < 4; ++r) {
      const int idx = t + 256 * r;          // 1024 float4
      const int m = idx >> 3, kc = idx & 7;
      const float4 v = *(const float4*)&A[(size_t)(m0 + m) * lda + k0 + 4 * kc];
      As[4 * kc + 0][m] = v.x; As[4 * kc + 1][m] = v.y;
      As[4 * kc + 2][m] = v.z; As[4 * kc + 3][m] = v.w;
    }
    if constexpr (!WT) {  // W[k*ldw + n], coalesced along n
      constexpr int NB4 = BN / 4;
      constexpr int TOT = BK * NB4;
#pragma unroll
      for (int r = 0; r < TOT / 256; ++r) {
        const int idx = t + 256 * r;
        const int k = idx / NB4, nc = idx % NB4;
        const float4 v = *(const float4*)&W[(size_t)(k0 + k) * ldw + n0 + 4 * nc];
        *(float4*)&Bs[k][4 * nc] = v;
      }
    } else {              // W[n*ldw + k], coalesced along k
      constexpr int TOT = BN * (BK / 4);
#pragma unroll
      for (int r = 0; r < TOT / 256; ++r) {
        const int idx = t + 256 * r;
        const int n = idx >> 3, kc = idx & 7;
        const float4 v = *(const float4*)&W[(size_t)(n0 + n) * ldw + k0 + 4 * kc];
        Bs[4 * kc + 0][n] = v.x; Bs[4 * kc + 1][n] = v.y;
        Bs[4 * kc + 2][n] = v.z; Bs[4 * kc + 3][n] = v.w;
      }
    }
    __syncthreads();
#pragma unroll 8
    for (int k = 0; k < BK; ++k) {
      const float4 a0 = *(const float4*)&As[k][tm * 8];
      const float4 a1 = *(const float4*)&As[k][tm * 8 + 4];
      const float ar[8] = {a0.x, a0.y, a0.z, a0.w, a1.x, a1.y, a1.z, a1.w};
      float br[TN];
#pragma unroll
      for (int j = 0; j < TN; j += 4) {
        const float4 b4 = *(const float4*)&Bs[k][tn * TN + j];
        br[j] = b4.x; br[j + 1] = b4.y; br[j + 2] = b4.z; br[j + 3] = b4.w;
      }
#pragma unroll
      for (int i = 0; i < 8; ++i)
#pragma unroll
        for (int j = 0; j < TN; ++j)
          acc[i][j] = fmaf(ar[i], br[j], acc[i][j]);
    }
    __syncthreads();
  }

  // epilogue
#pragma unroll
  for (int i = 0; i < 8; ++i) {
    const int row = m0 + tm * 8 + i;
#pragma unroll
    for (int j4 = 0; j4 < TN; j4 += 4) {
      const int col = n0 + tn * TN + j4;
      float vals[4];
      if constexpr (EPI != EPI_NONE) {
        const float4 b4 = *(const float4*)&bptr[col];
        vals[0] = acc[i][j4 + 0] + b4.x; vals[1] = acc[i][j4 + 1] + b4.y;
        vals[2] = acc[i][j4 + 2] + b4.z; vals[3] = acc[i][j4 + 3] + b4.w;
      } else {
#pragma unroll
        for (int j = 0; j < 4; ++j) vals[j] = acc[i][j4 + j];
      }
      if constexpr (EPI == EPI_QSCALE) {
#pragma unroll
        for (int j = 0; j < 4; ++j) vals[j] *= 0.125f;  // 1/sqrt(64)
      }
      if constexpr (EPI == EPI_GELU) {
#pragma unroll
        for (int j = 0; j < 4; ++j) vals[j] = gelu_f(vals[j]);
      }
      if constexpr (EPI == EPI_RES || EPI == EPI_FINAL) {
        const float4 r4 = *(const float4*)&res[(size_t)row * E + col];
        vals[0] += r4.x; vals[1] += r4.y; vals[2] += r4.z; vals[3] += r4.w;
      }
      if constexpr (EPI == EPI_FINAL) {
        const float4 s4 = *(const float4*)&ssum_in[(size_t)row * E + col];
        float4 so;
        so.x = s4.x * 0.9f + vals[0] * 0.1f;
        so.y = s4.y * 0.9f + vals[1] * 0.1f;
        so.z = s4.z * 0.9f + vals[2] * 0.1f;
        so.w = s4.w * 0.9f + vals[3] * 0.1f;
        *(float4*)&ssum_out[(size_t)row * E + col] = so;
      }
      *(float4*)&C[(size_t)row * ldc + col] = make_float4(vals[0], vals[1], vals[2], vals[3]);
    }
  }
}

}  // namespace

extern "C" void kernel_launch(void* const* d_in, const int* in_sizes, int n_in,
                              void* d_out, int out_size, void* d_ws, size_t ws_size,
                              hipStream_t stream) {
  const float* mem   = (const float*)d_in[0];
  const float* ssum  = (const float*)d_in[1];
  const float* x     = (const float*)d_in[2];
  const float* delta = (const float*)d_in[3];
  const float* ln1s  = (const float*)d_in[4];
  const float* ln1b  = (const float*)d_in[5];
  const float* wq    = (const float*)d_in[6];
  const float* bq    = (const float*)d_in[7];
  const float* wk    = (const float*)d_in[8];
  // d_in[9] = bk: constant over m in the logits -> softmax-invariant, unused.
  const float* wv    = (const float*)d_in[10];
  const float* bv    = (const float*)d_in[11];
  const float* wo    = (const float*)d_in[12];
  const float* bo    = (const float*)d_in[13];
  const float* ln2s  = (const float*)d_in[14];
  const float* ln2b  = (const float*)d_in[15];
  const float* w1    = (const float*)d_in[16];
  const float* b1    = (const float*)d_in[17];
  const float* w2    = (const float*)d_in[18];
  const float* b2    = (const float*)d_in[19];

  float* out_mem  = (float*)d_out;                       // [B,M,E]
  float* out_ssum = out_mem + (size_t)Bn * M * E;        // [B,E]
  float* out_x    = out_ssum + (size_t)Bn * E;           // [B,E]

  float* ws     = (float*)d_ws;                          // 272 MB total
  float* xin    = ws;                                    // B*E
  float* yln    = xin + (size_t)Bn * E;                  // B*E (LN1 then LN2)
  float* q      = yln + (size_t)Bn * E;                  // B*H*D
  float* qkc    = q + (size_t)Bn * E;                    // B*H*E (qk then ctx)
  float* o      = qkc + (size_t)Bn * H * E;              // B*H*D
  float* xmid   = o + (size_t)Bn * E;                    // B*E
  float* hidden = xmid + (size_t)Bn * E;                 // B*F

  // 1. x_in = x + delta; y = LN1(x_in)
  ln_kernel<true><<<Bn, 256, 0, stream>>>(x, delta, ln1s, ln1b, xin, yln);
  // 2. updated_mem
  memupd_kernel<<<4096, 256, 0, stream>>>((const float4*)mem, (const float4*)x,
                                          (const float4*)delta, (float4*)out_mem);
  // 3. q = (y@wq + bq)/8
  gemm_kernel<8, EPI_QSCALE, false><<<dim3(E / 128, Bn / 128, 1), 256, 0, stream>>>(
      yln, E, 0, wq, E, 0, bq, 0, q, E, 0, E, nullptr, nullptr, nullptr);
  // 4. qk[b,h,e] = sum_d q[b,h,d]*wk[e,h,d]   (per-head, W transposed layout)
  gemm_kernel<8, EPI_NONE, true><<<dim3(E / 128, Bn / 128, H), 256, 0, stream>>>(
      q, E, D, wk, E, D, nullptr, 0, qkc, H * E, E, D, nullptr, nullptr, nullptr);
  // 5. scores+softmax+ctx (in-place over qkc)
  attn_kernel<<<Bn, 256, 0, stream>>>(out_mem, qkc);
  // 6. o[b,h,d] = sum_e ctx*wv + bv          (per-head)
  gemm_kernel<4, EPI_BIAS, false><<<dim3(1, Bn / 128, H), 256, 0, stream>>>(
      qkc, H * E, E, wv, E, D, bv, D, o, E, D, E, nullptr, nullptr, nullptr);
  // 7. x_mid = o@wo + bo + x_in
  gemm_kernel<8, EPI_RES, false><<<dim3(E / 128, Bn / 128, 1), 256, 0, stream>>>(
      o, E, 0, wo, E, 0, bo, 0, xmid, E, 0, E, xin, nullptr, nullptr);
  // 8. y = LN2(x_mid)
  ln_kernel<false><<<Bn, 256, 0, stream>>>(xmid, nullptr, ln2s, ln2b, nullptr, yln);
  // 9. hidden = gelu(y@w1 + b1)
  gemm_kernel<8, EPI_GELU, false><<<dim3(F / 128, Bn / 128, 1), 256, 0, stream>>>(
      yln, E, 0, w1, F, 0, b1, 0, hidden, F, 0, E, nullptr, nullptr, nullptr);
  // 10. x_out = hidden@w2 + b2 + x_mid; new_ssum = ssum*0.9 + x_out*0.1
  gemm_kernel<8, EPI_FINAL, false><<<dim3(E / 128, Bn / 128, 1), 256, 0, stream>>>(
      hidden, F, 0, w2, E, 0, b2, 0, out_x, E, 0, F, xmid, ssum, out_ssum);
}

// Round 4
// 1029.024 us; speedup vs baseline: 1.6918x; 1.6918x over previous
//
#include <hip/hip_runtime.h>
#include <hip/hip_bf16.h>

// CWRRTCell — bf16-MFMA pipeline.
//  prep   : w1T/w2T transposed bf16 casts; wqkT[h]=wq*wk^T/8, wvoT[h]=wv*wo (folded
//           projections); bqk = bq@wk^T/8; bvo = bv@wo + bo.  (bk is softmax-invariant.)
//  ln1    : x_in = x+delta (f32), y = LN1 (bf16)
//  memupd : updated_mem -> d_out (f32, pure copy/append)
//  gemmQK : qk[b,(h,e')] = y @ wqkT + bqk          (bf16 out)   [8192,512]x[512,4096]
//  attn   : s = mem.qk, softmax, ctx = attn@mem    (bf16 out, in-place over qk)
//  gemmVO : x_mid = ctx @ wvoT + bvo + x_in        (f32 out)    [8192,4096]x[4096,512]
//  ln2    : y = LN2(x_mid) (bf16)
//  gemmG  : hidden = gelu(y@w1T + b1)              (bf16 out)   [8192,512]x[512,2048]
//  gemmF  : x_out = hidden@w2T + b2 + x_mid; ssum EMA           [8192,2048]x[2048,512]

namespace {

constexpr int Bn = 8192, E = 512, H = 8, D = 64, M = 16, F = 2048;

typedef unsigned short u16;
typedef __attribute__((ext_vector_type(8))) short s16x8;
typedef __attribute__((ext_vector_type(4))) float f32x4;

__device__ __forceinline__ float b2f(u16 u) {
  union { float f; unsigned int i; } w; w.i = ((unsigned int)u) << 16; return w.f;
}
__device__ __forceinline__ u16 f2b(float f) {  // round-to-nearest-even
  union { float f; unsigned int i; } w; w.f = f;
  return (u16)((w.i + 0x7fffu + ((w.i >> 16) & 1u)) >> 16);
}
__device__ __forceinline__ float gelu_f(float x) {
  // 0.5x(1+tanh(z)) == x*sigmoid(2z)
  float u = 1.5957691216057308f * (x + 0.044715f * x * x * x);
  return x / (1.0f + __expf(-u));
}
__device__ __forceinline__ void gld16(const u16* g, u16* l) {
  __builtin_amdgcn_global_load_lds(
      (const __attribute__((address_space(1))) void*)(uintptr_t)g,
      (__attribute__((address_space(3))) void*)l, 16, 0, 0);
}

// ---------------- LayerNorm: f32 in (optionally summed), bf16 y out --------
template <bool ADD>
__global__ __launch_bounds__(256)
void ln_kernel(const float* __restrict__ a, const float* __restrict__ bIn,
               const float* __restrict__ scale, const float* __restrict__ bias,
               float* __restrict__ xin_out, u16* __restrict__ y_out) {
  const int row = blockIdx.x;
  const int t   = threadIdx.x;
  float2 v = ((const float2*)(a + (size_t)row * E))[t];
  if constexpr (ADD) {
    float2 w = ((const float2*)(bIn + (size_t)row * E))[t];
    v.x += w.x; v.y += w.y;
    ((float2*)(xin_out + (size_t)row * E))[t] = v;
  }
  float s = v.x + v.y;
  float q = v.x * v.x + v.y * v.y;
#pragma unroll
  for (int o = 32; o > 0; o >>= 1) {
    s += __shfl_down(s, o);
    q += __shfl_down(q, o);
  }
  __shared__ float red[10];
  const int wave = t >> 6, lane = t & 63;
  if (lane == 0) { red[wave] = s; red[4 + wave] = q; }
  __syncthreads();
  if (t == 0) {
    float ts = red[0] + red[1] + red[2] + red[3];
    float tq = red[4] + red[5] + red[6] + red[7];
    float mu  = ts * (1.0f / E);
    float var = tq * (1.0f / E) - mu * mu;
    red[8] = mu;
    red[9] = rsqrtf(var + 1e-6f);
  }
  __syncthreads();
  const float mu = red[8], rs = red[9];
  float2 sc = ((const float2*)scale)[t];
  float2 bi = ((const float2*)bias)[t];
  ushort2 y;
  y.x = f2b((v.x - mu) * rs * sc.x + bi.x);
  y.y = f2b((v.y - mu) * rs * sc.y + bi.y);
  ((ushort2*)(y_out + (size_t)row * E))[t] = y;
}

// ---------------- memory roll: out[b,m,:] = m<15 ? mem[b,m+1,:] : x+delta --
__global__ __launch_bounds__(256)
void memupd_kernel(const float4* __restrict__ mem4, const float4* __restrict__ x4,
                   const float4* __restrict__ d4, float4* __restrict__ out4) {
  const size_t total  = (size_t)Bn * M * E / 4;
  const size_t stride = (size_t)gridDim.x * blockDim.x;
  for (size_t g = (size_t)blockIdx.x * blockDim.x + threadIdx.x; g < total; g += stride) {
    const int rem = (int)(g & 2047);
    float4 v;
    if (rem < 1920) {
      v = mem4[g + 128];
    } else {
      const size_t b = g >> 11;
      const int    c = rem & 127;
      float4 xv = x4[(b << 7) + c];
      float4 dv = d4[(b << 7) + c];
      v.x = xv.x + dv.x; v.y = xv.y + dv.y; v.z = xv.z + dv.z; v.w = xv.w + dv.w;
    }
    out4[g] = v;
  }
}

// ---------------- weight prep: W[K][N] f32 -> WT[N][K] bf16 ----------------
__global__ __launch_bounds__(256)
void transcast_kernel(const float* __restrict__ W, u16* __restrict__ WT,
                      int K, int N) {
  __shared__ float T[64][65];
  const int nb = blockIdx.x * 64, kb = blockIdx.y * 64;
  const int t = threadIdx.x;
#pragma unroll
  for (int i = 0; i < 4; ++i) {
    const int k = (t >> 4) + i * 16;
    const float4 v = *(const float4*)&W[(size_t)(kb + k) * N + nb + (t & 15) * 4];
    T[k][(t & 15) * 4 + 0] = v.x; T[k][(t & 15) * 4 + 1] = v.y;
    T[k][(t & 15) * 4 + 2] = v.z; T[k][(t & 15) * 4 + 3] = v.w;
  }
  __syncthreads();
  const int n = t & 63, kg = t >> 6;
  u16 buf[16];
#pragma unroll
  for (int j = 0; j < 16; ++j) buf[j] = f2b(T[kg * 16 + j][n]);
  u16* dst = &WT[(size_t)(nb + n) * K + kb + kg * 16];
  *(s16x8*)dst       = *(s16x8*)&buf[0];
  *(s16x8*)(dst + 8) = *(s16x8*)&buf[8];
}

// wqkT[(h*512+p)][e] = (1/8) sum_d wk[p,h,d]*wq[e,h,d]
__global__ __launch_bounds__(256)
void wqk_kernel(const float* __restrict__ wq, const float* __restrict__ wk,
                u16* __restrict__ out) {
  __shared__ float Q[64][65], Kk[64][65];
  const int h = blockIdx.z, e0 = blockIdx.x * 64, p0 = blockIdx.y * 64;
  const int t = threadIdx.x;
#pragma unroll
  for (int i = 0; i < 4; ++i) {
    const int r = (t >> 4) + i * 16;
    const float4 a = *(const float4*)&wq[((size_t)(e0 + r) * H + h) * D + (t & 15) * 4];
    Q[r][(t & 15) * 4 + 0] = a.x; Q[r][(t & 15) * 4 + 1] = a.y;
    Q[r][(t & 15) * 4 + 2] = a.z; Q[r][(t & 15) * 4 + 3] = a.w;
    const float4 b = *(const float4*)&wk[((size_t)(p0 + r) * H + h) * D + (t & 15) * 4];
    Kk[r][(t & 15) * 4 + 0] = b.x; Kk[r][(t & 15) * 4 + 1] = b.y;
    Kk[r][(t & 15) * 4 + 2] = b.z; Kk[r][(t & 15) * 4 + 3] = b.w;
  }
  __syncthreads();
  const int el = t & 63, pg = t >> 6;
#pragma unroll 4
  for (int i = 0; i < 16; ++i) {
    const int p = pg * 16 + i;
    float s = 0.f;
    for (int d = 0; d < 64; ++d) s = fmaf(Kk[p][d], Q[el][d], s);
    out[(size_t)(h * 512 + p0 + p) * 512 + e0 + el] = f2b(s * 0.125f);
  }
}

// wvoT[p][(h*512+e)] = sum_d wv[e,h,d]*wo[h,d,p]
__global__ __launch_bounds__(256)
void wvo_kernel(const float* __restrict__ wv, const float* __restrict__ wo,
                u16* __restrict__ out) {
  __shared__ float V[64][65], O[64][65];
  const int h = blockIdx.z, e0 = blockIdx.x * 64, p0 = blockIdx.y * 64;
  const int t = threadIdx.x;
#pragma unroll
  for (int i = 0; i < 4; ++i) {
    const int r = (t >> 4) + i * 16;
    const float4 a = *(const float4*)&wv[((size_t)(e0 + r) * H + h) * D + (t & 15) * 4];
    V[r][(t & 15) * 4 + 0] = a.x; V[r][(t & 15) * 4 + 1] = a.y;
    V[r][(t & 15) * 4 + 2] = a.z; V[r][(t & 15) * 4 + 3] = a.w;
    const float4 b = *(const float4*)&wo[(size_t)(h * D + r) * E + p0 + (t & 15) * 4];
    O[r][(t & 15) * 4 + 0] = b.x; O[r][(t & 15) * 4 + 1] = b.y;
    O[r][(t & 15) * 4 + 2] = b.z; O[r][(t & 15) * 4 + 3] = b.w;
  }
  __syncthreads();
  const int el = t & 63, pg = t >> 6;
#pragma unroll 4
  for (int i = 0; i < 16; ++i) {
    const int p = pg * 16 + i;
    float s = 0.f;
    for (int d = 0; d < 64; ++d) s = fmaf(V[el][d], O[d][p], s);
    out[(size_t)(p0 + p) * (H * E) + h * 512 + e0 + el] = f2b(s);
  }
}

// bqk[h*512+p] = (1/8) sum_d bq[h,d]*wk[p,h,d]
__global__ __launch_bounds__(256)
void bqk_kernel(const float* __restrict__ bq, const float* __restrict__ wk,
                float* __restrict__ out) {
  const int g = blockIdx.x * 256 + threadIdx.x;
  const int h = g >> 9, p = g & 511;
  float s = 0.f;
  for (int d = 0; d < 64; ++d) s = fmaf(bq[h * 64 + d], wk[((size_t)p * H + h) * D + d], s);
  out[g] = s * 0.125f;
}

// bvo[p] = bo[p] + sum_{h,d} bv[h,d]*wo[h,d,p]
__global__ __launch_bounds__(256)
void bvo_kernel(const float* __restrict__ bv, const float* __restrict__ wo,
                const float* __restrict__ bo, float* __restrict__ out) {
  const int p = blockIdx.x * 256 + threadIdx.x;
  float s = bo[p];
  for (int hd = 0; hd < H * D; ++hd) s = fmaf(bv[hd], wo[(size_t)hd * E + p], s);
  out[p] = s;
}

// ---------------- attention core (one block per b) -------------------------
__global__ __launch_bounds__(256)
void attn_kernel(const float* __restrict__ umem, const u16* __restrict__ qk,
                 u16* __restrict__ ctx) {
  __shared__ float memL[M * E];   // 32 KB
  __shared__ float qkL[H * E];    // 16 KB
  __shared__ float sL[H * M];
  __shared__ float attnL[H * M];
  const int b = blockIdx.x, t = threadIdx.x;

  const float4* um4 = (const float4*)(umem + (size_t)b * (M * E));
#pragma unroll
  for (int i = 0; i < 8; ++i) ((float4*)memL)[t + 256 * i] = um4[t + 256 * i];
  const s16x8* q8 = (const s16x8*)(qk + (size_t)b * (H * E));
#pragma unroll
  for (int i = 0; i < 2; ++i) {
    const s16x8 v = q8[t + 256 * i];
#pragma unroll
    for (int j = 0; j < 8; ++j) qkL[(t + 256 * i) * 8 + j] = b2f((u16)v[j]);
  }
  __syncthreads();

  // scores: 128 (h,m) pairs x 2 e-halves; lane-phased scalar reads
  {
    const int pair = t >> 1, h = pair >> 4, m = pair & 15, half = t & 1;
    const float* mp = memL + m * E + half * 256;
    const float* qp = qkL + h * E + half * 256;
    float s = 0.f;
    for (int i = 0; i < 256; ++i) {
      const int e = (i + t) & 255;
      s = fmaf(mp[e], qp[e], s);
    }
    s += __shfl_xor(s, 1);
    if (half == 0) sL[pair] = s;
  }
  __syncthreads();
  if (t < H) {
    float mx = sL[t * 16];
#pragma unroll
    for (int m = 1; m < 16; ++m) mx = fmaxf(mx, sL[t * 16 + m]);
    float ex[16], sum = 0.f;
#pragma unroll
    for (int m = 0; m < 16; ++m) { ex[m] = __expf(sL[t * 16 + m] - mx); sum += ex[m]; }
    const float inv = 1.0f / sum;
#pragma unroll
    for (int m = 0; m < 16; ++m) attnL[t * 16 + m] = ex[m] * inv;
  }
  __syncthreads();

  // ctx[h,e] = sum_m attn[h,m]*mem[m,e] -> bf16, in-place over qk buffer
#pragma unroll
  for (int j = 0; j < 4; ++j) {
    const int p4 = t + 256 * j;
    const int h  = p4 >> 7;
    const int e4 = p4 & 127;
    const float* ap = attnL + h * 16;
    float4 c = make_float4(0.f, 0.f, 0.f, 0.f);
#pragma unroll
    for (int m = 0; m < 16; ++m) {
      const float  a  = ap[m];
      const float4 mv = *(const float4*)&memL[m * E + 4 * e4];
      c.x = fmaf(a, mv.x, c.x); c.y = fmaf(a, mv.y, c.y);
      c.z = fmaf(a, mv.z, c.z); c.w = fmaf(a, mv.w, c.w);
    }
    ushort4 uv; uv.x = f2b(c.x); uv.y = f2b(c.y); uv.z = f2b(c.z); uv.w = f2b(c.w);
    *(ushort4*)&ctx[(size_t)b * (H * E) + 4 * p4] = uv;
  }
}

// ---------------- bf16 MFMA GEMM: C[M][N] = A[M][K] @ BT[N][K]^T + epi -----
// 128x128 tile, BK=32, 4 waves (each 64x64, 4x4 frags of 16x16x32).
enum : int { G_QK = 0, G_RES = 1, G_GELU = 2, G_FINAL = 3 };

template <int EPI>
__global__ __launch_bounds__(256)
void gemm_bf16(const u16* __restrict__ A, const u16* __restrict__ BT,
               const float* __restrict__ bias, void* __restrict__ Cout,
               int N, int K,
               const float* __restrict__ res, const float* __restrict__ ssum_in,
               float* __restrict__ ssum_out) {
  __shared__ __align__(16) u16 As[128 * 32];   // [row][k] 8 KB
  __shared__ __align__(16) u16 Bs[128 * 32];
  const int t  = threadIdx.x;
  const int l  = t & 63, w = t >> 6;
  const int m0 = blockIdx.y * 128;
  const int n0 = blockIdx.x * 128;

  // staging: thread t, issue i in {0,1}: LDS byte off = i*4096 + t*16
  // -> row = i*64 + (t>>2), k-granule = (t&3) (8 bf16 = 16 B)
  const int srow = t >> 2, skg = t & 3;
  const u16* Ag = A + (size_t)(m0 + srow) * K + skg * 8;
  const u16* Bg = BT + (size_t)(n0 + srow) * K + skg * 8;
  u16* AsT = As + t * 8;
  u16* BsT = Bs + t * 8;
  const size_t rowStep = (size_t)64 * K;

  const int wr = (w >> 1) * 64;   // wave row offset in tile
  const int wc = (w & 1) * 64;    // wave col offset
  const int fr = l & 15;
  const int kb = (l >> 4) * 8;    // k element offset within the 32-k row

  f32x4 acc[4][4] = {};

  for (int k0 = 0; k0 < K; k0 += 32) {
    gld16(Ag + k0, AsT);
    gld16(Ag + k0 + rowStep, AsT + 2048);
    gld16(Bg + k0, BsT);
    gld16(Bg + k0 + rowStep, BsT + 2048);
    __syncthreads();

    s16x8 af[4], bfr[4];
#pragma unroll
    for (int mf = 0; mf < 4; ++mf)
      af[mf] = *(const s16x8*)&As[(wr + mf * 16 + fr) * 32 + kb];
#pragma unroll
    for (int nf = 0; nf < 4; ++nf)
      bfr[nf] = *(const s16x8*)&Bs[(wc + nf * 16 + fr) * 32 + kb];
#pragma unroll
    for (int mf = 0; mf < 4; ++mf)
#pragma unroll
      for (int nf = 0; nf < 4; ++nf)
        acc[mf][nf] = __builtin_amdgcn_mfma_f32_16x16x32_bf16(af[mf], bfr[nf],
                                                              acc[mf][nf], 0, 0, 0);
    __syncthreads();
  }

  u16*   Cu = (u16*)Cout;
  float* Cf = (float*)Cout;
  float bcol[4];
#pragma unroll
  for (int nf = 0; nf < 4; ++nf) bcol[nf] = bias[n0 + wc + nf * 16 + fr];

#pragma unroll
  for (int mf = 0; mf < 4; ++mf) {
#pragma unroll
    for (int j = 0; j < 4; ++j) {
      const int row = m0 + wr + mf * 16 + (l >> 4) * 4 + j;
#pragma unroll
      for (int nf = 0; nf < 4; ++nf) {
        const int col = n0 + wc + nf * 16 + fr;
        float v = acc[mf][nf][j] + bcol[nf];
        if constexpr (EPI == G_GELU) v = gelu_f(v);
        if constexpr (EPI == G_RES || EPI == G_FINAL)
          v += res[(size_t)row * N + col];
        if constexpr (EPI == G_QK || EPI == G_GELU) {
          Cu[(size_t)row * N + col] = f2b(v);
        } else {
          Cf[(size_t)row * N + col] = v;
        }
        if constexpr (EPI == G_FINAL) {
          ssum_out[(size_t)row * N + col] =
              ssum_in[(size_t)row * N + col] * 0.9f + v * 0.1f;
        }
      }
    }
  }
}

}  // namespace

extern "C" void kernel_launch(void* const* d_in, const int* in_sizes, int n_in,
                              void* d_out, int out_size, void* d_ws, size_t ws_size,
                              hipStream_t stream) {
  const float* mem   = (const float*)d_in[0];
  const float* ssum  = (const float*)d_in[1];
  const float* x     = (const float*)d_in[2];
  const float* delta = (const float*)d_in[3];
  const float* ln1s  = (const float*)d_in[4];
  const float* ln1b  = (const float*)d_in[5];
  const float* wq    = (const float*)d_in[6];
  const float* bq    = (const float*)d_in[7];
  const float* wk    = (const float*)d_in[8];
  // d_in[9] = bk: softmax-invariant, unused.
  const float* wv    = (const float*)d_in[10];
  const float* bv    = (const float*)d_in[11];
  const float* wo    = (const float*)d_in[12];
  const float* bo    = (const float*)d_in[13];
  const float* ln2s  = (const float*)d_in[14];
  const float* ln2b  = (const float*)d_in[15];
  const float* w1    = (const float*)d_in[16];
  const float* b1    = (const float*)d_in[17];
  const float* w2    = (const float*)d_in[18];
  const float* b2    = (const float*)d_in[19];

  float* out_mem  = (float*)d_out;
  float* out_ssum = out_mem + (size_t)Bn * M * E;
  float* out_x    = out_ssum + (size_t)Bn * E;

  float* ws   = (float*)d_ws;
  float* xin  = ws;                         // B*E f32
  float* xmid = xin + (size_t)Bn * E;       // B*E f32
  float* bqk  = xmid + (size_t)Bn * E;      // 4096 f32
  float* bvo  = bqk + 4096;                 // 512 f32
  u16* yb   = (u16*)(bvo + 512);            // B*E bf16
  u16* qkc  = yb + (size_t)Bn * E;          // B*H*E bf16 (qk, then ctx in-place)
  u16* hid  = qkc + (size_t)Bn * H * E;     // B*F bf16
  u16* wqkT = hid + (size_t)Bn * F;         // [4096][512] bf16
  u16* wvoT = wqkT + (size_t)4096 * 512;    // [512][4096] bf16
  u16* w1T  = wvoT + (size_t)4096 * 512;    // [2048][512] bf16
  u16* w2T  = w1T + (size_t)2048 * 512;     // [512][2048] bf16

  // ---- weight prep (every call; harness re-poisons ws) ----
  transcast_kernel<<<dim3(F / 64, E / 64), 256, 0, stream>>>(w1, w1T, E, F);
  transcast_kernel<<<dim3(E / 64, F / 64), 256, 0, stream>>>(w2, w2T, F, E);
  wqk_kernel<<<dim3(8, 8, H), 256, 0, stream>>>(wq, wk, wqkT);
  wvo_kernel<<<dim3(8, 8, H), 256, 0, stream>>>(wv, wo, wvoT);
  bqk_kernel<<<16, 256, 0, stream>>>(bq, wk, bqk);
  bvo_kernel<<<2, 256, 0, stream>>>(bv, wo, bo, bvo);

  // ---- main pipeline ----
  ln_kernel<true><<<Bn, 256, 0, stream>>>(x, delta, ln1s, ln1b, xin, yb);
  memupd_kernel<<<4096, 256, 0, stream>>>((const float4*)mem, (const float4*)x,
                                          (const float4*)delta, (float4*)out_mem);
  gemm_bf16<G_QK><<<dim3(32, 64), 256, 0, stream>>>(
      yb, wqkT, bqk, qkc, H * E, E, nullptr, nullptr, nullptr);
  attn_kernel<<<Bn, 256, 0, stream>>>(out_mem, qkc, qkc);
  gemm_bf16<G_RES><<<dim3(4, 64), 256, 0, stream>>>(
      qkc, wvoT, bvo, xmid, E, H * E, xin, nullptr, nullptr);
  ln_kernel<false><<<Bn, 256, 0, stream>>>(xmid, nullptr, ln2s, ln2b, nullptr, yb);
  gemm_bf16<G_GELU><<<dim3(16, 64), 256, 0, stream>>>(
      yb, w1T, b1, hid, F, E, nullptr, nullptr, nullptr);
  gemm_bf16<G_FINAL><<<dim3(4, 64), 256, 0, stream>>>(
      hid, w2T, b2, out_x, E, F, xmid, ssum, out_ssum);
}